// Round 8
// baseline (739.457 us; speedup 1.0000x reference)
//
#include <hip/hip_runtime.h>
#include <cstdint>
#include <math.h>

// XLA CPU (no fast-math) emits unfused mul/add for all HLO-level elementwise ops.
#pragma clang fp contract(off)

#define DEV __device__ __forceinline__

typedef float f2 __attribute__((ext_vector_type(2)));

// ---------------------------------------------------------------- threefry2x32
struct U2 { unsigned a, b; };

DEV unsigned rotl32(unsigned v, int d) { return (v << d) | (v >> (32 - d)); }

DEV U2 tf2(unsigned k0, unsigned k1, unsigned x0, unsigned x1) {
  unsigned ks2 = k0 ^ k1 ^ 0x1BD11BDAu;
  x0 += k0; x1 += k1;
#define TFR(r) { x0 += x1; x1 = rotl32(x1, r); x1 ^= x0; }
  TFR(13) TFR(15) TFR(26) TFR(6)
  x0 += k1; x1 += ks2 + 1u;
  TFR(17) TFR(29) TFR(16) TFR(24)
  x0 += ks2; x1 += k0 + 2u;
  TFR(13) TFR(15) TFR(26) TFR(6)
  x0 += k0; x1 += k1 + 3u;
  TFR(17) TFR(29) TFR(16) TFR(24)
  x0 += k1; x1 += ks2 + 4u;
  TFR(13) TFR(15) TFR(26) TFR(6)
  x0 += ks2; x1 += k0 + 5u;
#undef TFR
  U2 r; r.a = x0; r.b = x1; return r;
}

DEV unsigned rbits(unsigned k0, unsigned k1, unsigned idx) {
  U2 o = tf2(k0, k1, 0u, idx);
  return o.a ^ o.b;
}

DEV float u01(unsigned bits) {
  return __uint_as_float((bits >> 9) | 0x3F800000u) - 1.0f;
}

// ---------------------------------------------------------------- XLA CPU math (scalar)
DEV float xla_exp(float xi) {
  float x = fminf(fmaxf(xi, -88.3762626647949f), 88.3762626647950f);
  float fx = floorf(x * 1.44269504088896341f + 0.5f);
  float tmp = 0.693359375f * fx;
  float z = -2.12194440e-4f * fx;
  x = x - tmp;
  x = x - z;
  z = x * x;
  float y = 1.9875691500e-4f * x + 1.3981999507e-3f;
  y = y * x + 8.3334519073e-3f;
  y = y * x + 4.1665795894e-2f;
  y = y * x + 1.6666665459e-1f;
  y = y * x + 5.0000001201e-1f;
  y = y * z + x;
  y = y + 1.0f;
  int n = (int)fx;
  float two_n = __uint_as_float((unsigned)(n + 127) << 23);
  return fmaxf(y * two_n, xi);
}

DEV float xla_log(float xi) {
  float xc = fmaxf(xi, 1.17549435082228751e-38f);
  unsigned bits = __float_as_uint(xc);
  float e = (float)((int)(bits >> 23) - 126);
  float m = __uint_as_float((bits & 0x007FFFFFu) | 0x3F000000u);
  bool msk = m < 0.707106781186547524f;
  float tmp = msk ? m : 0.0f;
  float em  = msk ? 1.0f : 0.0f;
  m = m - 1.0f;
  e = e - em;
  m = m + tmp;
  float z  = m * m;
  float x3 = z * m;
  float y0 = 7.0376836292e-2f  * m + -1.1514610310e-1f;
  float y1 = -1.2420140846e-1f * m + 1.4249322787e-1f;
  float y2 = 2.0000714765e-1f  * m + -2.4999993993e-1f;
  y0 = y0 * m + 1.1676998740e-1f;
  y1 = y1 * m + -1.6668057665e-1f;
  y2 = y2 * m + 3.3333331174e-1f;
  y0 = y0 * x3 + y1;
  y0 = y0 * x3 + y2;
  y0 = y0 * x3;
  y0 = -2.12194440e-4f * e + y0;
  y0 = y0 - 0.5f * z;
  float r = m + y0;
  r = 0.693359375f * e + r;
  if (!(xi > 0.0f)) r = (xi == 0.0f) ? -__builtin_inff() : __builtin_nanf("");
  if (xi == __builtin_inff()) r = __builtin_inff();
  return r;
}

DEV float xla_tanh(float x) {
  float xc = fminf(fmaxf(x, -9.0f), 9.0f);
  float x2 = xc * xc;
  float p = x2 * -2.76076847742355e-16f + 2.00018790482477e-13f;
  p = p * x2 + -8.60467152213735e-11f;
  p = p * x2 + 5.12229709037114e-08f;
  p = p * x2 + 1.48572235717979e-05f;
  p = p * x2 + 6.37261928875436e-04f;
  p = p * x2 + 4.89352455891786e-03f;
  p = xc * p;
  float q = x2 * 1.19825839466702e-06f + 1.18534705686654e-04f;
  q = q * x2 + 2.26843463243900e-03f;
  q = q * x2 + 4.89352518554385e-03f;
  float r = p / q;
  return (fabsf(x) < 0.0004f) ? x : r;
}

// ---------------------------------------------------------------- packed-pair math
// Bit-exact per component vs the scalar versions (v_pk_* are IEEE per-lane-pair).
DEV f2 xla_tanh_2(f2 x) {
  f2 xc = __builtin_elementwise_min(__builtin_elementwise_max(x, (f2)(-9.0f)), (f2)9.0f);
  f2 x2 = xc * xc;
  f2 p = x2 * (f2)(-2.76076847742355e-16f) + (f2)2.00018790482477e-13f;
  p = p * x2 + (f2)(-8.60467152213735e-11f);
  p = p * x2 + (f2)5.12229709037114e-08f;
  p = p * x2 + (f2)1.48572235717979e-05f;
  p = p * x2 + (f2)6.37261928875436e-04f;
  p = p * x2 + (f2)4.89352455891786e-03f;
  p = xc * p;
  f2 q = x2 * (f2)1.19825839466702e-06f + (f2)1.18534705686654e-04f;
  q = q * x2 + (f2)2.26843463243900e-03f;
  q = q * x2 + (f2)4.89352518554385e-03f;
  f2 r;
  r.x = p.x / q.x;
  r.y = p.y / q.y;
  r.x = (fabsf(x.x) < 0.0004f) ? x.x : r.x;
  r.y = (fabsf(x.y) < 0.0004f) ? x.y : r.y;
  return r;
}

DEV f2 xla_exp_2(f2 xi) {
  f2 x = __builtin_elementwise_min(__builtin_elementwise_max(xi, (f2)(-88.3762626647949f)),
                                   (f2)88.3762626647950f);
  f2 fx = __builtin_elementwise_floor(x * (f2)1.44269504088896341f + (f2)0.5f);
  f2 tmp = (f2)0.693359375f * fx;
  f2 z = (f2)(-2.12194440e-4f) * fx;
  x = x - tmp;
  x = x - z;
  z = x * x;
  f2 y = (f2)1.9875691500e-4f * x + (f2)1.3981999507e-3f;
  y = y * x + (f2)8.3334519073e-3f;
  y = y * x + (f2)4.1665795894e-2f;
  y = y * x + (f2)1.6666665459e-1f;
  y = y * x + (f2)5.0000001201e-1f;
  y = y * z + x;
  y = y + (f2)1.0f;
  int n0 = (int)fx.x;
  int n1 = (int)fx.y;
  f2 two_n;
  two_n.x = __uint_as_float((unsigned)(n0 + 127) << 23);
  two_n.y = __uint_as_float((unsigned)(n1 + 127) << 23);
  f2 r = y * two_n;
  return __builtin_elementwise_max(r, xi);
}

DEV float sqrt_cr(float x) { return (float)sqrt((double)x); }

DEV float xla_log1p(float x) {
  float fl = xla_log(x + 1.0f);
  float fs = ((-0.5f) * x + 1.0f) * x;
  return (fabsf(x) < 1e-4f) ? fs : fl;
}

DEV float softplus_ref(float x) {
  float amax = fmaxf(x, 0.0f);
  return amax + xla_log1p(xla_exp(-fabsf(x)));
}

DEV float xla_erfinv(float x) {
  float w = -xla_log1p(-(x * x));
  bool lt = w < 5.0f;
  float wa = lt ? (w - 2.5f) : (sqrt_cr(w) - 3.0f);
  float p;
  if (lt) {
    p = 2.81022636e-08f;
    p = p * wa + 3.43273939e-07f;
    p = p * wa + -3.5233877e-06f;
    p = p * wa + -4.39150654e-06f;
    p = p * wa + 0.00021858087f;
    p = p * wa + -0.00125372503f;
    p = p * wa + -0.00417768164f;
    p = p * wa + 0.246640727f;
    p = p * wa + 1.50140941f;
  } else {
    p = -0.000200214257f;
    p = p * wa + 0.000100950558f;
    p = p * wa + 0.00134934322f;
    p = p * wa + -0.00367342844f;
    p = p * wa + 0.00573950773f;
    p = p * wa + -0.0076224613f;
    p = p * wa + 0.00943887047f;
    p = p * wa + 1.00167406f;
    p = p * wa + 2.83297682f;
  }
  return p * x;
}

// ---------------------------------------------------------------- custom f64 pow (validated R6/R7)
DEV float powm_fast(float xf) {
  const double E = (double)((float)(-1.0 / 1.2));
  double x = (double)xf;
  long long bits = __double_as_longlong(x);
  int k = (int)((bits >> 52) & 0x7FFLL) - 1023;
  double m = __longlong_as_double((bits & 0x000FFFFFFFFFFFFFLL) | 0x3FF0000000000000LL);
  if (m > 1.4142135623730951) { m = m * 0.5; k = k + 1; }
  double z = (m - 1.0) / (m + 1.0);
  double z2 = z * z;
  double pl = 0.11541560327111707;
  pl = fma(pl, z2, 0.12545174268599682);
  pl = fma(pl, z2, 0.13739952770371080);
  pl = fma(pl, z2, 0.15186263588304878);
  pl = fma(pl, z2, 0.16972882833987805);
  pl = fma(pl, z2, 0.19235933878519512);
  pl = fma(pl, z2, 0.22195308321368668);
  pl = fma(pl, z2, 0.26230818925253880);
  pl = fma(pl, z2, 0.32059889797532520);
  pl = fma(pl, z2, 0.41219858311113240);
  pl = fma(pl, z2, 0.57707801635558537);
  pl = fma(pl, z2, 0.96179669392597556);
  pl = fma(pl, z2, 2.88539008177792681);
  double t = (double)k + z * pl;
  double yh = E * t;
  double yl = fma(E, t, -yh);
  double fn = floor(yh + 0.5);
  double f = yh - fn;
  double w = f * 0.69314718055994531;
  double ew = 1.6059043836821613e-10;
  ew = fma(ew, w, 2.0876756987868099e-9);
  ew = fma(ew, w, 2.5052108385441719e-8);
  ew = fma(ew, w, 2.7557319223985893e-7);
  ew = fma(ew, w, 2.7557319223985888e-6);
  ew = fma(ew, w, 2.4801587301587302e-5);
  ew = fma(ew, w, 1.9841269841269841e-4);
  ew = fma(ew, w, 1.3888888888888889e-3);
  ew = fma(ew, w, 8.3333333333333332e-3);
  ew = fma(ew, w, 4.1666666666666664e-2);
  ew = fma(ew, w, 0.16666666666666666);
  ew = fma(ew, w, 0.5);
  ew = fma(ew, w, 1.0);
  ew = fma(ew, w, 1.0);
  int n = (int)fn;
  double r = ew * __longlong_as_double((long long)(n + 1023) << 52);
  r = fma(r, yl * 0.69314718055994531, r);
  return (float)r;
}

// ---------------------------------------------------------------- constants
#define SIG2F  0.0025000000000000005f
#define RATE1F 13.207443270509278f
#define LO_N  -0.99999994039535522f
#define SQRT2F 1.4142135623730951f
#define Tn 64

// ---------------------------------------------------------------- ws layout (floats)
#define F_A      0
#define F_B      2048
#define F_DS     4096
#define F_KEYS   4128
#define F_KA     4640
#define F_KP     5664
#define F_SUB    6688
#define F_SCALED 16384
#define F_QUAD   4210688
#define F_RP2    8404992
#define F_SQ     16793600
#define F_U2     25182208
#define F_Z      33570816
#define F_LK     34619392
#define F_END    35733504   // 143 MB — proven available (R5)

// ---------------------------------------------------------------- phi + keys
__global__ void __launch_bounds__(64) phikey_kernel(
    const float* __restrict__ tseq,
    const float* __restrict__ pW1, const float* __restrict__ pb1,
    const float* __restrict__ pW2, const float* __restrict__ pb2,
    const float* __restrict__ pW3, const float* __restrict__ pb3,
    const float* __restrict__ diff_log, float* __restrict__ ws) {
  unsigned* wsu = (unsigned*)ws;
  __shared__ float h1[64], h2[64];
  __shared__ unsigned lk[64][2];
  int t = blockIdx.x, w = threadIdx.x;

  if (t == 0) {
    if (w == 0) {
      unsigned k0 = 0u, k1 = 42u;   // jax.random.key(42)
      for (int i = 0; i < 64; ++i) {
        lk[i][0] = k0; lk[i][1] = k1;
        U2 c0 = tf2(k0, k1, 0u, 0u);
        k0 = c0.a; k1 = c0.b;
      }
    }
    __syncthreads();
    unsigned k0 = lk[w][0], k1 = lk[w][1];
    U2 c1 = tf2(k0, k1, 0u, 1u);
    U2 c2 = tf2(k0, k1, 0u, 2u);
    U2 c3 = tf2(k0, k1, 0u, 3u);
    U2 c4 = tf2(k0, k1, 0u, 4u);
    wsu[F_KEYS + w * 8 + 0] = c1.a; wsu[F_KEYS + w * 8 + 1] = c1.b;
    wsu[F_KEYS + w * 8 + 2] = c2.a; wsu[F_KEYS + w * 8 + 3] = c2.b;
    wsu[F_KEYS + w * 8 + 4] = c3.a; wsu[F_KEYS + w * 8 + 5] = c3.b;
    wsu[F_KEYS + w * 8 + 6] = c4.a; wsu[F_KEYS + w * 8 + 7] = c4.b;
    unsigned a0 = c3.a, a1 = c3.b;
    for (int a = 0; a < 8; ++a) {
      U2 kp = tf2(a0, a1, 0u, 1u);
      U2 ka = tf2(a0, a1, 0u, 2u);
      U2 nx = tf2(a0, a1, 0u, 0u);
      wsu[F_KP + (w * 8 + a) * 2 + 0] = kp.a; wsu[F_KP + (w * 8 + a) * 2 + 1] = kp.b;
      wsu[F_KA + (w * 8 + a) * 2 + 0] = ka.a; wsu[F_KA + (w * 8 + a) * 2 + 1] = ka.b;
      a0 = nx.a; a1 = nx.b;
    }
    unsigned r0 = c2.a, r1 = c2.b;
    for (int k = 0; k < 17; ++k) {
      U2 sub = tf2(r0, r1, 0u, 1u);
      U2 nx  = tf2(r0, r1, 0u, 0u);
      wsu[F_SUB + (w * 17 + k) * 2 + 0] = sub.a; wsu[F_SUB + (w * 17 + k) * 2 + 1] = sub.b;
      r0 = nx.a; r1 = nx.b;
    }
    __syncthreads();
  }

  float tv = tseq[t];
  h1[w] = xla_tanh(tv * pW1[w] + pb1[w]);
  __syncthreads();
  float acc = 0.0f;
  for (int k = 0; k < 64; ++k) acc = fmaf(h1[k], pW2[k * 64 + w], acc);
  acc = acc + pb2[w];
  h2[w] = xla_tanh(acc);
  __syncthreads();
  acc = 0.0f;
  for (int k = 0; k < 64; ++k) acc = fmaf(h2[k], pW3[k * 64 + w], acc);
  acc = acc + pb3[w];
  if (w < 32) ws[F_A + t * 32 + w] = -softplus_ref(acc);
  else        ws[F_B + t * 32 + (w - 32)] = acc;
  if (t == 0 && w < 32) ws[F_DS + w] = softplus_ref(diff_log[w]);
}

// ---------------------------------------------------------------- stable precompute
__global__ void __launch_bounds__(256) stable2_kernel(const unsigned* __restrict__ wsu,
                                                      float* __restrict__ ws) {
  int t = blockIdx.y;
  int u = blockIdx.x * 256 + threadIdx.x;
  if (u < 65536) {
    int b_ = u >> 11, e = u & 2047, d = e & 31;
    unsigned k0 = wsu[F_KEYS + t * 8 + 0], k1 = wsu[F_KEYS + t * 8 + 1];
    float uu = u01(rbits(k0, k1, (unsigned)(b_ * 2048 + e)));
    float raw = 0.1f * powm_fast(1.0f - uu);
    float scaled = ws[F_DS + d] * raw;
    float A = ws[F_A + t * 32 + d];
    ws[F_SCALED + t * 65536 + u] = scaled;
    ws[F_QUAD   + t * 65536 + u] = A * (scaled * scaled);
  } else if (u < 196608) {
    int i = u - 65536;
    int b_ = i >> 12, jd = (i >> 3) & 511, a = i & 7, d = jd & 31;
    unsigned p0 = wsu[F_KP + (t * 8 + a) * 2], p1 = wsu[F_KP + (t * 8 + a) * 2 + 1];
    float rp = 0.1f * powm_fast(1.0f - u01(rbits(p0, p1, (unsigned)(b_ * 512 + jd))));
    float rp2 = rp * rp;
    float A = ws[F_A + t * 32 + d];
    float den = fmaxf(1.0f - ((2.0f * A) * rp2) * SIG2F, 1e-6f);
    unsigned a0 = wsu[F_KA + (t * 8 + a) * 2], a1 = wsu[F_KA + (t * 8 + a) * 2 + 1];
    ws[F_RP2 + t * 131072 + i] = rp2;
    ws[F_SQ  + t * 131072 + i] = sqrt_cr(den);
    ws[F_U2  + t * 131072 + i] = u01(rbits(a0, a1, (unsigned)(b_ * 512 + jd)));
  } else if (u < 212992) {
    int i = u - 196608;
    int b_ = i >> 9, jd = i & 511;
    unsigned g0 = wsu[F_KEYS + t * 8 + 6], g1 = wsu[F_KEYS + t * 8 + 7];
    float fz = u01(rbits(g0, g1, (unsigned)(b_ * 512 + jd)));
    float un = fmaxf(LO_N, fz * 2.0f + LO_N);
    ws[F_Z + t * 16384 + i] = SQRT2F * xla_erfinv(un);
  } else {
    int i = u - 212992;
    int b_ = i >> 5, d = i & 31;
    float L = 0.0f;
    for (int k = 0; k < 17; ++k) {
      unsigned s0 = wsu[F_SUB + (t * 17 + k) * 2], s1 = wsu[F_SUB + (t * 17 + k) * 2 + 1];
      L = L + xla_log(u01(rbits(s0, s1, (unsigned)(b_ * 32 + d))));
      ws[F_LK + ((t * 32 + b_) * 17 + k) * 32 + d] = L;
    }
  }
}

// ---------------------------------------------------------------- sim: 3 barriers/step, packed math
__global__ void __launch_bounds__(1024) sim5_kernel(
    const float* __restrict__ state_init, const float* __restrict__ tseq,
    const float* __restrict__ gW1, const float* __restrict__ gb1,
    const float* __restrict__ gW2, const float* __restrict__ gb2,
    const float* __restrict__ gW3, const float* __restrict__ gb3,
    const float* __restrict__ ws, float* __restrict__ out) {
  const int b = blockIdx.x;
  const int tid = threadIdx.x;

  __shared__ float sW1[33 * 64], sB1[64], sW2[64 * 64], sB2[64], sW3[64 * 32], sB3[32];
  __shared__ float sTseq[64];
  __shared__ float sX[32], sK1[32], sA[32], sMb[32], sDrift[32], sDs[32];
  __shared__ float sH1[64], sH2[64];
  __shared__ float sTilt[32 * 65];
  __shared__ float sCond[512];

  for (int i = tid; i < 33 * 64; i += 1024) sW1[i] = gW1[i];
  for (int i = tid; i < 64 * 64; i += 1024) sW2[i] = gW2[i];
  for (int i = tid; i < 64 * 32; i += 1024) sW3[i] = gW3[i];
  if (tid < 64) { sB1[tid] = gb1[tid]; sB2[tid] = gb2[tid]; sTseq[tid] = tseq[tid]; }
  if (tid < 32) {
    sB3[tid] = gb3[tid];
    sDs[tid] = ws[F_DS + tid];
    float X0 = state_init[b * 32 + tid];
    sX[tid] = X0;
    float A = ws[F_A + tid], Bv = ws[F_B + tid];
    sA[tid] = A;
    float K1 = (2.0f * A) * X0 + Bv;
    sK1[tid] = K1;
    sMb[tid] = xla_exp((-(K1 * K1)) / (4.0f * A));
  }

  const int lane = tid & 63;
  const int gbase = lane & 56;
  const int jdm = (tid >> 3) + (tid & 3) * 128;

  // register-strided slab offsets (current step)
  const float* __restrict__ pSc = ws + F_SCALED + b * 2048 + tid;
  const float* __restrict__ pQd = ws + F_QUAD   + b * 2048 + tid;
  const float* __restrict__ pRp = ws + F_RP2    + b * 4096 + tid;
  const float* __restrict__ pSq = ws + F_SQ     + b * 4096 + tid;
  const float* __restrict__ pU2 = ws + F_U2     + b * 4096 + tid;
  const float* __restrict__ pZ  = ws + F_Z      + b * 512 + jdm;
  const float* __restrict__ pLk = ws + F_LK     + b * 544 + (tid & 31);

  // prefetch step 0
  float cSc0, cSc1, cSc2, cQd0, cQd1, cQd2, cRp2[4], cSq[4], cU2[4];
  {
    cSc0 = pSc[0];
    cQd0 = pQd[0];
    cSc1 = (tid < 960) ? pSc[960] : 0.0f;
    cQd1 = (tid < 960) ? pQd[960] : 0.0f;
    cSc2 = (tid < 128) ? pSc[1920] : 0.0f;
    cQd2 = (tid < 128) ? pQd[1920] : 0.0f;
#pragma unroll
    for (int q = 0; q < 4; ++q) {
      cRp2[q] = pRp[q * 1024];
      cSq[q]  = pSq[q * 1024];
      cU2[q]  = pU2[q * 1024];
    }
  }
  __syncthreads();

  float past_t = sTseq[0];
  for (int ti = 0; ti < Tn; ++ti) {
    float t = sTseq[ti];
    float dt = t - past_t;

    // ---- step-top: this step's plk + z; next step's slab
    float plk[17];
    if (tid < 32) {
#pragma unroll
      for (int k = 0; k < 17; ++k) plk[k] = pLk[k * 32];
    }
    float zm = pZ[0];

    int adv = (ti < 63) ? 1 : 0;
    int aS = adv * 65536;     // scaled/quad stride
    int aC = adv * 131072;    // candidate stride
    float nSc0, nSc1, nSc2, nQd0, nQd1, nQd2, nRp2[4], nSq[4], nU2[4];
    float nA = 0.0f, nB = 0.0f;
    {
      nSc0 = pSc[aS];
      nQd0 = pQd[aS];
      nSc1 = (tid < 960) ? pSc[aS + 960] : 0.0f;
      nQd1 = (tid < 960) ? pQd[aS + 960] : 0.0f;
      nSc2 = (tid < 128) ? pSc[aS + 1920] : 0.0f;
      nQd2 = (tid < 128) ? pQd[aS + 1920] : 0.0f;
#pragma unroll
      for (int q = 0; q < 4; ++q) {
        nRp2[q] = pRp[aC + q * 1024];
        nSq[q]  = pSq[aC + q * 1024];
        nU2[q]  = pU2[aC + q * 1024];
      }
      int tn = ti + adv;
      if (tid < 32) { nA = ws[F_A + tn * 32 + tid]; nB = ws[F_B + tn * 32 + tid]; }
    }

    // ---- P1: waves 0-14 tilt (packed pairs); wave 15 drift MLP
    if (tid >= 960) {
      int l = tid - 960;
      float acc = 0.0f;
      acc = fmaf(t, sW1[l], acc);
      for (int k = 1; k < 33; ++k) acc = fmaf(sX[k - 1], sW1[k * 64 + l], acc);
      acc = acc + sB1[l];
      sH1[l] = xla_tanh(acc);
      float acc2 = 0.0f;
      for (int k = 0; k < 64; ++k) acc2 = fmaf(sH1[k], sW2[k * 64 + l], acc2);
      acc2 = acc2 + sB2[l];
      sH2[l] = xla_tanh(acc2);
      if (l < 32) {
        float a3 = 0.0f;
        for (int k = 0; k < 64; ++k) a3 = fmaf(sH2[k], sW3[k * 32 + l], a3);
        sDrift[l] = a3 + sB3[l];
      }
    } else {
      int d = tid & 31;
      float K1 = sK1[d];
      {
        float lin = K1 * cSc0;
        f2 a; a.x = (cQd0 + lin) / 80.0f; a.y = (cQd0 - lin) / 80.0f;
        f2 th = xla_tanh_2(a);
        f2 ex = xla_exp_2((f2)80.0f * th);
        sTilt[d * 65 + (tid >> 5)] = ex.x + ex.y;
      }
      {
        float lin = K1 * cSc1;
        f2 a; a.x = (cQd1 + lin) / 80.0f; a.y = (cQd1 - lin) / 80.0f;
        f2 th = xla_tanh_2(a);
        f2 ex = xla_exp_2((f2)80.0f * th);
        sTilt[d * 65 + (tid >> 5) + 30] = ex.x + ex.y;
      }
      if (tid < 128) {
        float lin = K1 * cSc2;
        f2 a; a.x = (cQd2 + lin) / 80.0f; a.y = (cQd2 - lin) / 80.0f;
        f2 th = xla_tanh_2(a);
        f2 ex = xla_exp_2((f2)80.0f * th);
        sTilt[d * 65 + (tid >> 5) + 60] = ex.x + ex.y;
      }
    }
    __syncthreads();   // B1

    // ---- P2: quantile clip + candidates (packed exps) + in-wave select + 1 cond/lane
    {
      int wv = tid >> 6;
      float vo0 = sTilt[wv * 65 + lane];
      float vo1 = sTilt[(wv + 16) * 65 + lane];
      float w0 = vo0, w1 = vo1;
      float s0_59 = 0.0f, s0_60 = 0.0f, s1_59 = 0.0f, s1_60 = 0.0f;
#pragma unroll
      for (int it = 0; it < 5; ++it) {
        float m0 = w0, m1 = w1;
#pragma unroll
        for (int j = 1; j < 64; j <<= 1) {
          m0 = fmaxf(m0, __shfl_xor(m0, j, 64));
          m1 = fmaxf(m1, __shfl_xor(m1, j, 64));
        }
        if (it == 3) { s0_60 = m0; s1_60 = m1; }
        if (it == 4) { s0_59 = m0; s1_59 = m1; }
        if (it < 4) {
          unsigned long long b0 = __ballot(w0 == m0);
          unsigned long long b1 = __ballot(w1 == m1);
          int l0 = __ffsll(b0) - 1;
          int l1 = __ffsll(b1) - 1;
          if (lane == l0) w0 = -1.0f;
          if (lane == l1) w1 = -1.0f;
        }
      }
      float qv = 0.95f * 63.0f;
      float hw = qv - 59.0f;
      float lw = 1.0f - hw;
      float tq0 = s0_59 * lw + s0_60 * hw;
      float tq1 = s1_59 * lw + s1_60 * hw;
      sTilt[wv * 65 + lane] = fminf(vo0, tq0);
      sTilt[(wv + 16) * 65 + lane] = fminf(vo1, tq1);

      // candidates: d identical for all 4 q
      int d = (tid >> 3) & 31;
      float A = sA[d], K1 = sK1[d], Mb = sMb[d];
      float K1sq = K1 * K1;
      float arg[4];
#pragma unroll
      for (int q = 0; q < 4; ++q) {
        float rp2 = cRp2[q];
        float den = fmaxf(1.0f - ((2.0f * A) * rp2) * SIG2F, 1e-6f);
        arg[q] = ((K1sq * rp2) * SIG2F) / (2.0f * den);
      }
      f2 e01, e23;
      { f2 a01; a01.x = arg[0]; a01.y = arg[1]; e01 = xla_exp_2(a01); }
      { f2 a23; a23.x = arg[2]; a23.y = arg[3]; e23 = xla_exp_2(a23); }
      float Cvv[4];
      Cvv[0] = e01.x / cSq[0];
      Cvv[1] = e01.y / cSq[1];
      Cvv[2] = e23.x / cSq[2];
      Cvv[3] = e23.y / cSq[3];
      float rsel[4];
#pragma unroll
      for (int q = 0; q < 4; ++q) {
        float p = fminf(Cvv[q] / Mb, 1.0f);
        bool acc = (cU2[q] < p);
        unsigned long long m = __ballot(acc);
        unsigned grp = (unsigned)((m >> gbase) & 0xFFull);
        int first = (grp != 0u) ? (__ffs(grp) - 1) : 0;
        float got = __shfl(cRp2[q], gbase + first, 64);
        rsel[q] = (grp != 0u) ? got : (0.1f * 0.1f);
      }
      int myq = tid & 3;
      float rp2m = rsel[0];
      rp2m = (myq == 1) ? rsel[1] : rp2m;
      rp2m = (myq == 2) ? rsel[2] : rp2m;
      rp2m = (myq == 3) ? rsel[3] : rp2m;
      float t2 = (2.0f * rp2m) * SIG2F;
      float K2 = A - 1.0f / t2;
      float K2s = (K2 < -1e-6f) ? K2 : -1e-6f;
      float mean = (-K1) / (2.0f * K2s);
      float var = (-1.0f) / (2.0f * K2s);
      float cond = mean + sqrtf(var) * zm;
      if ((tid & 7) < 4) sCond[jdm] = cond;
    }
    __syncthreads();   // B2

    // ---- P3: poisson + masked in-order sum + state update
    if (tid < 32) {
      int d = tid;
      float sum = 0.0f;
      for (int s = 0; s < 64; ++s) sum = sum + sTilt[d * 65 + s];
      float tilt = sum / 64.0f;
      float lam = (tilt * RATE1F) * dt;
      float negl = -lam;
      int n = 0;
#pragma unroll
      for (int k = 0; k < 17; ++k) n += (plk[k] > negl) ? 1 : 0;
      float soj = 0.0f;
      for (int j = 0; j < 16; ++j) {
        float cv = sCond[j * 32 + d];
        soj = soj + cv * ((j < n) ? 1.0f : 0.0f);
      }
      soj = 2.5f * xla_tanh(soj / 2.5f);
      float Xn = (sX[d] + sDrift[d] * dt) + sDs[d] * soj;
      sX[d] = Xn;
      out[ti * 1024 + b * 32 + d] = Xn;
      sA[d] = nA;
      float K1n = (2.0f * nA) * Xn + nB;
      sK1[d] = K1n;
      sMb[d] = xla_exp((-(K1n * K1n)) / (4.0f * nA));
    }
    __syncthreads();   // B3

    cSc0 = nSc0; cSc1 = nSc1; cSc2 = nSc2;
    cQd0 = nQd0; cQd1 = nQd1; cQd2 = nQd2;
#pragma unroll
    for (int q = 0; q < 4; ++q) { cRp2[q] = nRp2[q]; cSq[q] = nSq[q]; cU2[q] = nU2[q]; }
    pSc += aS; pQd += aS; pRp += aC; pSq += aC; pU2 += aC;
    pZ += adv * 16384; pLk += adv * 17408;
    past_t = t;
  }
}

// ---------------------------------------------------------------- launch
extern "C" void kernel_launch(void* const* d_in, const int* in_sizes, int n_in,
                              void* d_out, int out_size, void* d_ws, size_t ws_size,
                              hipStream_t stream) {
  const float* state_init = (const float*)d_in[0];
  const float* tseq       = (const float*)d_in[1];
  const float* dW1        = (const float*)d_in[2];
  const float* db1        = (const float*)d_in[3];
  const float* dW2        = (const float*)d_in[4];
  const float* db2        = (const float*)d_in[5];
  const float* dW3        = (const float*)d_in[6];
  const float* db3        = (const float*)d_in[7];
  const float* diff_log   = (const float*)d_in[8];
  const float* pW1        = (const float*)d_in[9];
  const float* pb1        = (const float*)d_in[10];
  const float* pW2        = (const float*)d_in[11];
  const float* pb2        = (const float*)d_in[12];
  const float* pW3        = (const float*)d_in[13];
  const float* pb3        = (const float*)d_in[14];
  float* ws = (float*)d_ws;
  unsigned* wsu = (unsigned*)d_ws;

  phikey_kernel<<<64, 64, 0, stream>>>(tseq, pW1, pb1, pW2, pb2, pW3, pb3, diff_log, ws);
  stable2_kernel<<<dim3(836, 64), 256, 0, stream>>>(wsu, ws);
  sim5_kernel<<<32, 1024, 0, stream>>>(state_init, tseq, dW1, db1, dW2, db2,
                                       dW3, db3, ws, (float*)d_out);
}

// Round 9
// 688.361 us; speedup vs baseline: 1.0742x; 1.0742x over previous
//
#include <hip/hip_runtime.h>
#include <cstdint>
#include <math.h>

// XLA CPU (no fast-math) emits unfused mul/add for all HLO-level elementwise ops.
#pragma clang fp contract(off)

#define DEV __device__ __forceinline__

// ---------------------------------------------------------------- threefry2x32
struct U2 { unsigned a, b; };

DEV unsigned rotl32(unsigned v, int d) { return (v << d) | (v >> (32 - d)); }

DEV U2 tf2(unsigned k0, unsigned k1, unsigned x0, unsigned x1) {
  unsigned ks2 = k0 ^ k1 ^ 0x1BD11BDAu;
  x0 += k0; x1 += k1;
#define TFR(r) { x0 += x1; x1 = rotl32(x1, r); x1 ^= x0; }
  TFR(13) TFR(15) TFR(26) TFR(6)
  x0 += k1; x1 += ks2 + 1u;
  TFR(17) TFR(29) TFR(16) TFR(24)
  x0 += ks2; x1 += k0 + 2u;
  TFR(13) TFR(15) TFR(26) TFR(6)
  x0 += k0; x1 += k1 + 3u;
  TFR(17) TFR(29) TFR(16) TFR(24)
  x0 += k1; x1 += ks2 + 4u;
  TFR(13) TFR(15) TFR(26) TFR(6)
  x0 += ks2; x1 += k0 + 5u;
#undef TFR
  U2 r; r.a = x0; r.b = x1; return r;
}

DEV unsigned rbits(unsigned k0, unsigned k1, unsigned idx) {
  U2 o = tf2(k0, k1, 0u, idx);
  return o.a ^ o.b;
}

DEV float u01(unsigned bits) {
  return __uint_as_float((bits >> 9) | 0x3F800000u) - 1.0f;
}

// ---------------------------------------------------------------- XLA CPU math
DEV float xla_exp(float xi) {
  float x = fminf(fmaxf(xi, -88.3762626647949f), 88.3762626647950f);
  float fx = floorf(x * 1.44269504088896341f + 0.5f);
  float tmp = 0.693359375f * fx;
  float z = -2.12194440e-4f * fx;
  x = x - tmp;
  x = x - z;
  z = x * x;
  float y = 1.9875691500e-4f * x + 1.3981999507e-3f;
  y = y * x + 8.3334519073e-3f;
  y = y * x + 4.1665795894e-2f;
  y = y * x + 1.6666665459e-1f;
  y = y * x + 5.0000001201e-1f;
  y = y * z + x;
  y = y + 1.0f;
  int n = (int)fx;
  float two_n = __uint_as_float((unsigned)(n + 127) << 23);
  return fmaxf(y * two_n, xi);
}

DEV float xla_log(float xi) {
  float xc = fmaxf(xi, 1.17549435082228751e-38f);
  unsigned bits = __float_as_uint(xc);
  float e = (float)((int)(bits >> 23) - 126);
  float m = __uint_as_float((bits & 0x007FFFFFu) | 0x3F000000u);
  bool msk = m < 0.707106781186547524f;
  float tmp = msk ? m : 0.0f;
  float em  = msk ? 1.0f : 0.0f;
  m = m - 1.0f;
  e = e - em;
  m = m + tmp;
  float z  = m * m;
  float x3 = z * m;
  float y0 = 7.0376836292e-2f  * m + -1.1514610310e-1f;
  float y1 = -1.2420140846e-1f * m + 1.4249322787e-1f;
  float y2 = 2.0000714765e-1f  * m + -2.4999993993e-1f;
  y0 = y0 * m + 1.1676998740e-1f;
  y1 = y1 * m + -1.6668057665e-1f;
  y2 = y2 * m + 3.3333331174e-1f;
  y0 = y0 * x3 + y1;
  y0 = y0 * x3 + y2;
  y0 = y0 * x3;
  y0 = -2.12194440e-4f * e + y0;
  y0 = y0 - 0.5f * z;
  float r = m + y0;
  r = 0.693359375f * e + r;
  if (!(xi > 0.0f)) r = (xi == 0.0f) ? -__builtin_inff() : __builtin_nanf("");
  if (xi == __builtin_inff()) r = __builtin_inff();
  return r;
}

DEV float xla_tanh(float x) {
  float xc = fminf(fmaxf(x, -9.0f), 9.0f);
  float x2 = xc * xc;
  float p = x2 * -2.76076847742355e-16f + 2.00018790482477e-13f;
  p = p * x2 + -8.60467152213735e-11f;
  p = p * x2 + 5.12229709037114e-08f;
  p = p * x2 + 1.48572235717979e-05f;
  p = p * x2 + 6.37261928875436e-04f;
  p = p * x2 + 4.89352455891786e-03f;
  p = xc * p;
  float q = x2 * 1.19825839466702e-06f + 1.18534705686654e-04f;
  q = q * x2 + 2.26843463243900e-03f;
  q = q * x2 + 4.89352518554385e-03f;
  float r = p / q;
  return (fabsf(x) < 0.0004f) ? x : r;
}

DEV float sqrt_cr(float x) { return (float)sqrt((double)x); }

DEV float xla_log1p(float x) {
  float fl = xla_log(x + 1.0f);
  float fs = ((-0.5f) * x + 1.0f) * x;
  return (fabsf(x) < 1e-4f) ? fs : fl;
}

DEV float softplus_ref(float x) {
  float amax = fmaxf(x, 0.0f);
  return amax + xla_log1p(xla_exp(-fabsf(x)));
}

DEV float xla_erfinv(float x) {
  float w = -xla_log1p(-(x * x));
  bool lt = w < 5.0f;
  float wa = lt ? (w - 2.5f) : (sqrt_cr(w) - 3.0f);
  float p;
  if (lt) {
    p = 2.81022636e-08f;
    p = p * wa + 3.43273939e-07f;
    p = p * wa + -3.5233877e-06f;
    p = p * wa + -4.39150654e-06f;
    p = p * wa + 0.00021858087f;
    p = p * wa + -0.00125372503f;
    p = p * wa + -0.00417768164f;
    p = p * wa + 0.246640727f;
    p = p * wa + 1.50140941f;
  } else {
    p = -0.000200214257f;
    p = p * wa + 0.000100950558f;
    p = p * wa + 0.00134934322f;
    p = p * wa + -0.00367342844f;
    p = p * wa + 0.00573950773f;
    p = p * wa + -0.0076224613f;
    p = p * wa + 0.00943887047f;
    p = p * wa + 1.00167406f;
    p = p * wa + 2.83297682f;
  }
  return p * x;
}

// ---------------------------------------------------------------- custom f64 pow (validated R6/R7)
DEV float powm_fast(float xf) {
  const double E = (double)((float)(-1.0 / 1.2));
  double x = (double)xf;
  long long bits = __double_as_longlong(x);
  int k = (int)((bits >> 52) & 0x7FFLL) - 1023;
  double m = __longlong_as_double((bits & 0x000FFFFFFFFFFFFFLL) | 0x3FF0000000000000LL);
  if (m > 1.4142135623730951) { m = m * 0.5; k = k + 1; }
  double z = (m - 1.0) / (m + 1.0);
  double z2 = z * z;
  double pl = 0.11541560327111707;
  pl = fma(pl, z2, 0.12545174268599682);
  pl = fma(pl, z2, 0.13739952770371080);
  pl = fma(pl, z2, 0.15186263588304878);
  pl = fma(pl, z2, 0.16972882833987805);
  pl = fma(pl, z2, 0.19235933878519512);
  pl = fma(pl, z2, 0.22195308321368668);
  pl = fma(pl, z2, 0.26230818925253880);
  pl = fma(pl, z2, 0.32059889797532520);
  pl = fma(pl, z2, 0.41219858311113240);
  pl = fma(pl, z2, 0.57707801635558537);
  pl = fma(pl, z2, 0.96179669392597556);
  pl = fma(pl, z2, 2.88539008177792681);
  double t = (double)k + z * pl;
  double yh = E * t;
  double yl = fma(E, t, -yh);
  double fn = floor(yh + 0.5);
  double f = yh - fn;
  double w = f * 0.69314718055994531;
  double ew = 1.6059043836821613e-10;
  ew = fma(ew, w, 2.0876756987868099e-9);
  ew = fma(ew, w, 2.5052108385441719e-8);
  ew = fma(ew, w, 2.7557319223985893e-7);
  ew = fma(ew, w, 2.7557319223985888e-6);
  ew = fma(ew, w, 2.4801587301587302e-5);
  ew = fma(ew, w, 1.9841269841269841e-4);
  ew = fma(ew, w, 1.3888888888888889e-3);
  ew = fma(ew, w, 8.3333333333333332e-3);
  ew = fma(ew, w, 4.1666666666666664e-2);
  ew = fma(ew, w, 0.16666666666666666);
  ew = fma(ew, w, 0.5);
  ew = fma(ew, w, 1.0);
  ew = fma(ew, w, 1.0);
  int n = (int)fn;
  double r = ew * __longlong_as_double((long long)(n + 1023) << 52);
  r = fma(r, yl * 0.69314718055994531, r);
  return (float)r;
}

// ---------------------------------------------------------------- constants
#define SIG2F  0.0025000000000000005f
#define RATE1F 13.207443270509278f
#define LO_N  -0.99999994039535522f
#define SQRT2F 1.4142135623730951f
#define Tn 64

// ---------------------------------------------------------------- ws layout (floats)
#define F_A      0
#define F_B      2048
#define F_DS     4096
#define F_KEYS   4128
#define F_KA     4640
#define F_KP     5664
#define F_SUB    6688
#define F_SCALED 16384
#define F_QUAD   4210688
#define F_RP2    8404992
#define F_SQ     16793600
#define F_U2     25182208
#define F_Z      33570816
#define F_LK     34619392
#define F_END    35733504   // 143 MB — proven available (R5)
#define NRAW 4194304
#define NZ   1048576
#define NLK  65536

// ---------------------------------------------------------------- phi + keys
__global__ void __launch_bounds__(64) phikey_kernel(
    const float* __restrict__ tseq,
    const float* __restrict__ pW1, const float* __restrict__ pb1,
    const float* __restrict__ pW2, const float* __restrict__ pb2,
    const float* __restrict__ pW3, const float* __restrict__ pb3,
    const float* __restrict__ diff_log, float* __restrict__ ws) {
  unsigned* wsu = (unsigned*)ws;
  __shared__ float h1[64], h2[64];
  __shared__ unsigned lk[64][2];
  int t = blockIdx.x, w = threadIdx.x;

  if (t == 0) {
    if (w == 0) {
      unsigned k0 = 0u, k1 = 42u;   // jax.random.key(42)
      for (int i = 0; i < 64; ++i) {
        lk[i][0] = k0; lk[i][1] = k1;
        U2 c0 = tf2(k0, k1, 0u, 0u);
        k0 = c0.a; k1 = c0.b;
      }
    }
    __syncthreads();
    unsigned k0 = lk[w][0], k1 = lk[w][1];
    U2 c1 = tf2(k0, k1, 0u, 1u);
    U2 c2 = tf2(k0, k1, 0u, 2u);
    U2 c3 = tf2(k0, k1, 0u, 3u);
    U2 c4 = tf2(k0, k1, 0u, 4u);
    wsu[F_KEYS + w * 8 + 0] = c1.a; wsu[F_KEYS + w * 8 + 1] = c1.b;
    wsu[F_KEYS + w * 8 + 2] = c2.a; wsu[F_KEYS + w * 8 + 3] = c2.b;
    wsu[F_KEYS + w * 8 + 4] = c3.a; wsu[F_KEYS + w * 8 + 5] = c3.b;
    wsu[F_KEYS + w * 8 + 6] = c4.a; wsu[F_KEYS + w * 8 + 7] = c4.b;
    unsigned a0 = c3.a, a1 = c3.b;
    for (int a = 0; a < 8; ++a) {
      U2 kp = tf2(a0, a1, 0u, 1u);
      U2 ka = tf2(a0, a1, 0u, 2u);
      U2 nx = tf2(a0, a1, 0u, 0u);
      wsu[F_KP + (w * 8 + a) * 2 + 0] = kp.a; wsu[F_KP + (w * 8 + a) * 2 + 1] = kp.b;
      wsu[F_KA + (w * 8 + a) * 2 + 0] = ka.a; wsu[F_KA + (w * 8 + a) * 2 + 1] = ka.b;
      a0 = nx.a; a1 = nx.b;
    }
    unsigned r0 = c2.a, r1 = c2.b;
    for (int k = 0; k < 17; ++k) {
      U2 sub = tf2(r0, r1, 0u, 1u);
      U2 nx  = tf2(r0, r1, 0u, 0u);
      wsu[F_SUB + (w * 17 + k) * 2 + 0] = sub.a; wsu[F_SUB + (w * 17 + k) * 2 + 1] = sub.b;
      r0 = nx.a; r1 = nx.b;
    }
    __syncthreads();
  }

  float tv = tseq[t];
  h1[w] = xla_tanh(tv * pW1[w] + pb1[w]);
  __syncthreads();
  float acc = 0.0f;
  for (int k = 0; k < 64; ++k) acc = fmaf(h1[k], pW2[k * 64 + w], acc);
  acc = acc + pb2[w];
  h2[w] = xla_tanh(acc);
  __syncthreads();
  acc = 0.0f;
  for (int k = 0; k < 64; ++k) acc = fmaf(h2[k], pW3[k * 64 + w], acc);
  acc = acc + pb3[w];
  if (w < 32) ws[F_A + t * 32 + w] = -softplus_ref(acc);
  else        ws[F_B + t * 32 + (w - 32)] = acc;
  if (t == 0 && w < 32) ws[F_DS + w] = softplus_ref(diff_log[w]);
}

// ---------------------------------------------------------------- stable precompute (ILP: 3 chains/thread)
// NRAW threads. Thread i: tilt unit i, cand units i and i+NRAW; first NZ threads
// also z unit i; last NLK threads also lk unit. Outputs byte-identical to R7.
__global__ void __launch_bounds__(256) stable2b_kernel(const unsigned* __restrict__ wsu,
                                                       float* __restrict__ ws) {
  int i = blockIdx.x * 256 + threadIdx.x;

  // ---- tilt chain: global unit i
  int tt = i >> 16, ut = i & 65535;
  {
    int b_ = ut >> 11, e = ut & 2047, d = e & 31;
    unsigned k0 = wsu[F_KEYS + tt * 8 + 0], k1 = wsu[F_KEYS + tt * 8 + 1];
    float uu = u01(rbits(k0, k1, (unsigned)(b_ * 2048 + e)));
    float raw = 0.1f * powm_fast(1.0f - uu);
    float scaled = ws[F_DS + d] * raw;
    float A = ws[F_A + tt * 32 + d];
    ws[F_SCALED + i] = scaled;
    ws[F_QUAD   + i] = A * (scaled * scaled);
  }

  // ---- cand chains: global units g1 = i, g2 = i + NRAW
#pragma unroll
  for (int h = 0; h < 2; ++h) {
    int g = i + h * NRAW;
    int t = g >> 17, i2 = g & 131071;
    int b_ = i2 >> 12, jd = (i2 >> 3) & 511, a = i2 & 7, d = jd & 31;
    unsigned p0 = wsu[F_KP + (t * 8 + a) * 2], p1 = wsu[F_KP + (t * 8 + a) * 2 + 1];
    float rp = 0.1f * powm_fast(1.0f - u01(rbits(p0, p1, (unsigned)(b_ * 512 + jd))));
    float rp2 = rp * rp;
    float A = ws[F_A + t * 32 + d];
    float den = fmaxf(1.0f - ((2.0f * A) * rp2) * SIG2F, 1e-6f);
    unsigned a0 = wsu[F_KA + (t * 8 + a) * 2], a1 = wsu[F_KA + (t * 8 + a) * 2 + 1];
    ws[F_RP2 + g] = rp2;
    ws[F_SQ  + g] = sqrt_cr(den);
    ws[F_U2  + g] = u01(rbits(a0, a1, (unsigned)(b_ * 512 + jd)));
  }

  // ---- z tail (threads 0..NZ-1)
  if (i < NZ) {
    int t = i >> 14, i4 = i & 16383;
    int b_ = i4 >> 9, jd = i4 & 511;
    unsigned g0 = wsu[F_KEYS + t * 8 + 6], g1 = wsu[F_KEYS + t * 8 + 7];
    float fz = u01(rbits(g0, g1, (unsigned)(b_ * 512 + jd)));
    float un = fmaxf(LO_N, fz * 2.0f + LO_N);
    ws[F_Z + i] = SQRT2F * xla_erfinv(un);
  }

  // ---- lk tail (threads NRAW-NLK .. NRAW-1)
  if (i >= NRAW - NLK) {
    int i5 = i - (NRAW - NLK);
    int t = i5 >> 10, w5 = i5 & 1023;
    int b_ = w5 >> 5, d = w5 & 31;
    float L = 0.0f;
    for (int k = 0; k < 17; ++k) {
      unsigned s0 = wsu[F_SUB + (t * 17 + k) * 2], s1 = wsu[F_SUB + (t * 17 + k) * 2 + 1];
      L = L + xla_log(u01(rbits(s0, s1, (unsigned)(b_ * 32 + d))));
      ws[F_LK + ((t * 32 + b_) * 17 + k) * 32 + d] = L;
    }
  }
}

// ---------------------------------------------------------------- sim: 3 barriers/step (R7 sim4, verbatim)
__global__ void __launch_bounds__(1024) sim4_kernel(
    const float* __restrict__ state_init, const float* __restrict__ tseq,
    const float* __restrict__ gW1, const float* __restrict__ gb1,
    const float* __restrict__ gW2, const float* __restrict__ gb2,
    const float* __restrict__ gW3, const float* __restrict__ gb3,
    const float* __restrict__ ws, float* __restrict__ out) {
  const int b = blockIdx.x;
  const int tid = threadIdx.x;

  __shared__ float sW1[33 * 64], sB1[64], sW2[64 * 64], sB2[64], sW3[64 * 32], sB3[32];
  __shared__ float sTseq[64];
  __shared__ float sX[32], sK1[32], sA[32], sMb[32], sDrift[32], sDs[32];
  __shared__ float sH1[64], sH2[64];
  __shared__ float sTilt[32 * 65];
  __shared__ float sCond[512];

  for (int i = tid; i < 33 * 64; i += 1024) sW1[i] = gW1[i];
  for (int i = tid; i < 64 * 64; i += 1024) sW2[i] = gW2[i];
  for (int i = tid; i < 64 * 32; i += 1024) sW3[i] = gW3[i];
  if (tid < 64) { sB1[tid] = gb1[tid]; sB2[tid] = gb2[tid]; sTseq[tid] = tseq[tid]; }
  if (tid < 32) {
    sB3[tid] = gb3[tid];
    sDs[tid] = ws[F_DS + tid];
    float X0 = state_init[b * 32 + tid];
    sX[tid] = X0;
    float A = ws[F_A + tid], Bv = ws[F_B + tid];
    sA[tid] = A;
    float K1 = (2.0f * A) * X0 + Bv;
    sK1[tid] = K1;
    sMb[tid] = xla_exp((-(K1 * K1)) / (4.0f * A));
  }

  // prefetch step 0
  float cSc0, cSc1, cSc2, cQd0, cQd1, cQd2, cRp2[4], cSq[4], cU2[4];
  {
    int tb = b;
    cSc0 = ws[F_SCALED + tb * 2048 + tid];
    cQd0 = ws[F_QUAD + tb * 2048 + tid];
    cSc1 = (tid < 960) ? ws[F_SCALED + tb * 2048 + 960 + tid] : 0.0f;
    cQd1 = (tid < 960) ? ws[F_QUAD + tb * 2048 + 960 + tid] : 0.0f;
    cSc2 = (tid < 128) ? ws[F_SCALED + tb * 2048 + 1920 + tid] : 0.0f;
    cQd2 = (tid < 128) ? ws[F_QUAD + tb * 2048 + 1920 + tid] : 0.0f;
#pragma unroll
    for (int q = 0; q < 4; ++q) {
      cRp2[q] = ws[F_RP2 + tb * 4096 + tid + q * 1024];
      cSq[q]  = ws[F_SQ + tb * 4096 + tid + q * 1024];
      cU2[q]  = ws[F_U2 + tb * 4096 + tid + q * 1024];
    }
  }
  __syncthreads();

  const int lane = tid & 63;
  const int gbase = lane & 56;          // 8-lane group base within wave
  const int jdm = (tid >> 3) + (tid & 3) * 128;   // my cond assignment

  float past_t = sTseq[0];
  for (int ti = 0; ti < Tn; ++ti) {
    float t = sTseq[ti];
    float dt = t - past_t;

    // ---- step-top prefetches: this step's plk + z, next step's slab
    float plk[17];
    if (tid < 32) {
#pragma unroll
      for (int k = 0; k < 17; ++k) plk[k] = ws[F_LK + ((ti * 32 + b) * 17 + k) * 32 + tid];
    }
    float zm = ws[F_Z + (ti * 32 + b) * 512 + jdm];

    int tn = (ti < 63) ? ti + 1 : 63;
    float nSc0, nSc1, nSc2, nQd0, nQd1, nQd2, nRp2[4], nSq[4], nU2[4];
    float nA = 0.0f, nB = 0.0f;
    {
      int tb = tn * 32 + b;
      nSc0 = ws[F_SCALED + tb * 2048 + tid];
      nQd0 = ws[F_QUAD + tb * 2048 + tid];
      nSc1 = (tid < 960) ? ws[F_SCALED + tb * 2048 + 960 + tid] : 0.0f;
      nQd1 = (tid < 960) ? ws[F_QUAD + tb * 2048 + 960 + tid] : 0.0f;
      nSc2 = (tid < 128) ? ws[F_SCALED + tb * 2048 + 1920 + tid] : 0.0f;
      nQd2 = (tid < 128) ? ws[F_QUAD + tb * 2048 + 1920 + tid] : 0.0f;
#pragma unroll
      for (int q = 0; q < 4; ++q) {
        nRp2[q] = ws[F_RP2 + tb * 4096 + tid + q * 1024];
        nSq[q]  = ws[F_SQ + tb * 4096 + tid + q * 1024];
        nU2[q]  = ws[F_U2 + tb * 4096 + tid + q * 1024];
      }
      if (tid < 32) { nA = ws[F_A + tn * 32 + tid]; nB = ws[F_B + tn * 32 + tid]; }
    }

    // ---- P1: waves 0-14 tilt; wave 15 drift MLP (same-wave LDS)
    if (tid >= 960) {
      int l = tid - 960;
      float acc = 0.0f;
      acc = fmaf(t, sW1[l], acc);
      for (int k = 1; k < 33; ++k) acc = fmaf(sX[k - 1], sW1[k * 64 + l], acc);
      acc = acc + sB1[l];
      sH1[l] = xla_tanh(acc);
      float acc2 = 0.0f;
      for (int k = 0; k < 64; ++k) acc2 = fmaf(sH1[k], sW2[k * 64 + l], acc2);
      acc2 = acc2 + sB2[l];
      sH2[l] = xla_tanh(acc2);
      if (l < 32) {
        float a3 = 0.0f;
        for (int k = 0; k < 64; ++k) a3 = fmaf(sH2[k], sW3[k * 32 + l], a3);
        sDrift[l] = a3 + sB3[l];
      }
    } else {
      // d is identical for all three tasks (960 and 1920 are multiples of 32)
      int d = tid & 31;
      float K1 = sK1[d];
      {
        float lin = K1 * cSc0;
        float lh = 80.0f * xla_tanh((cQd0 + lin) / 80.0f);
        float nh = 80.0f * xla_tanh((cQd0 - lin) / 80.0f);
        sTilt[d * 65 + (tid >> 5)] = xla_exp(lh) + xla_exp(nh);
      }
      {
        float lin = K1 * cSc1;
        float lh = 80.0f * xla_tanh((cQd1 + lin) / 80.0f);
        float nh = 80.0f * xla_tanh((cQd1 - lin) / 80.0f);
        sTilt[d * 65 + (tid >> 5) + 30] = xla_exp(lh) + xla_exp(nh);
      }
      if (tid < 128) {
        float lin = K1 * cSc2;
        float lh = 80.0f * xla_tanh((cQd2 + lin) / 80.0f);
        float nh = 80.0f * xla_tanh((cQd2 - lin) / 80.0f);
        sTilt[d * 65 + (tid >> 5) + 60] = xla_exp(lh) + xla_exp(nh);
      }
    }
    __syncthreads();   // B1

    // ---- P2: quantile clip (2 d's/wave) + candidates + in-wave select + 1 cond/lane
    {
      // quantile via 5 max-extractions
      int wv = tid >> 6;
      float vo0 = sTilt[wv * 65 + lane];
      float vo1 = sTilt[(wv + 16) * 65 + lane];
      float w0 = vo0, w1 = vo1;
      float s0_59 = 0.0f, s0_60 = 0.0f, s1_59 = 0.0f, s1_60 = 0.0f;
#pragma unroll
      for (int it = 0; it < 5; ++it) {
        float m0 = w0, m1 = w1;
#pragma unroll
        for (int j = 1; j < 64; j <<= 1) {
          m0 = fmaxf(m0, __shfl_xor(m0, j, 64));
          m1 = fmaxf(m1, __shfl_xor(m1, j, 64));
        }
        if (it == 3) { s0_60 = m0; s1_60 = m1; }
        if (it == 4) { s0_59 = m0; s1_59 = m1; }
        if (it < 4) {
          unsigned long long b0 = __ballot(w0 == m0);
          unsigned long long b1 = __ballot(w1 == m1);
          int l0 = __ffsll(b0) - 1;
          int l1 = __ffsll(b1) - 1;
          if (lane == l0) w0 = -1.0f;
          if (lane == l1) w1 = -1.0f;
        }
      }
      float qv = 0.95f * 63.0f;
      float hw = qv - 59.0f;
      float lw = 1.0f - hw;
      float tq0 = s0_59 * lw + s0_60 * hw;
      float tq1 = s1_59 * lw + s1_60 * hw;
      sTilt[wv * 65 + lane] = fminf(vo0, tq0);
      sTilt[(wv + 16) * 65 + lane] = fminf(vo1, tq1);

      // candidates: d identical for all 4 q (q*128 ≡ 0 mod 32)
      int d = (tid >> 3) & 31;
      float A = sA[d], K1 = sK1[d], Mb = sMb[d];
      float K1sq = K1 * K1;
      float rsel[4];
#pragma unroll
      for (int q = 0; q < 4; ++q) {
        float rp2 = cRp2[q];
        float den = fmaxf(1.0f - ((2.0f * A) * rp2) * SIG2F, 1e-6f);
        float Cv = xla_exp(((K1sq * rp2) * SIG2F) / (2.0f * den)) / cSq[q];
        float p = fminf(Cv / Mb, 1.0f);
        bool acc = (cU2[q] < p);
        unsigned long long m = __ballot(acc);
        unsigned grp = (unsigned)((m >> gbase) & 0xFFull);
        int first = (grp != 0u) ? (__ffs(grp) - 1) : 0;
        float got = __shfl(rp2, gbase + first, 64);
        rsel[q] = (grp != 0u) ? got : (0.1f * 0.1f);
      }
      // one cond per lane: myq = tid&3 (lanes 4-7 duplicate 0-3, store-masked)
      int myq = tid & 3;
      float rp2m = rsel[0];
      rp2m = (myq == 1) ? rsel[1] : rp2m;
      rp2m = (myq == 2) ? rsel[2] : rp2m;
      rp2m = (myq == 3) ? rsel[3] : rp2m;
      float t2 = (2.0f * rp2m) * SIG2F;
      float K2 = A - 1.0f / t2;
      float K2s = (K2 < -1e-6f) ? K2 : -1e-6f;
      float mean = (-K1) / (2.0f * K2s);
      float var = (-1.0f) / (2.0f * K2s);
      float cond = mean + sqrtf(var) * zm;
      if ((tid & 7) < 4) sCond[jdm] = cond;
    }
    __syncthreads();   // B2

    // ---- P3: poisson (prefetched plk) + masked in-order sum + state update
    if (tid < 32) {
      int d = tid;
      float sum = 0.0f;
      for (int s = 0; s < 64; ++s) sum = sum + sTilt[d * 65 + s];
      float tilt = sum / 64.0f;
      float lam = (tilt * RATE1F) * dt;
      float negl = -lam;
      int n = 0;
#pragma unroll
      for (int k = 0; k < 17; ++k) n += (plk[k] > negl) ? 1 : 0;
      float soj = 0.0f;
      for (int j = 0; j < 16; ++j) {
        float cv = sCond[j * 32 + d];
        soj = soj + cv * ((j < n) ? 1.0f : 0.0f);
      }
      soj = 2.5f * xla_tanh(soj / 2.5f);
      float Xn = (sX[d] + sDrift[d] * dt) + sDs[d] * soj;
      sX[d] = Xn;
      out[ti * 1024 + b * 32 + d] = Xn;
      sA[d] = nA;
      float K1n = (2.0f * nA) * Xn + nB;
      sK1[d] = K1n;
      sMb[d] = xla_exp((-(K1n * K1n)) / (4.0f * nA));
    }
    __syncthreads();   // B3

    cSc0 = nSc0; cSc1 = nSc1; cSc2 = nSc2;
    cQd0 = nQd0; cQd1 = nQd1; cQd2 = nQd2;
#pragma unroll
    for (int q = 0; q < 4; ++q) { cRp2[q] = nRp2[q]; cSq[q] = nSq[q]; cU2[q] = nU2[q]; }
    past_t = t;
  }
}

// ---------------------------------------------------------------- launch
extern "C" void kernel_launch(void* const* d_in, const int* in_sizes, int n_in,
                              void* d_out, int out_size, void* d_ws, size_t ws_size,
                              hipStream_t stream) {
  const float* state_init = (const float*)d_in[0];
  const float* tseq       = (const float*)d_in[1];
  const float* dW1        = (const float*)d_in[2];
  const float* db1        = (const float*)d_in[3];
  const float* dW2        = (const float*)d_in[4];
  const float* db2        = (const float*)d_in[5];
  const float* dW3        = (const float*)d_in[6];
  const float* db3        = (const float*)d_in[7];
  const float* diff_log   = (const float*)d_in[8];
  const float* pW1        = (const float*)d_in[9];
  const float* pb1        = (const float*)d_in[10];
  const float* pW2        = (const float*)d_in[11];
  const float* pb2        = (const float*)d_in[12];
  const float* pW3        = (const float*)d_in[13];
  const float* pb3        = (const float*)d_in[14];
  float* ws = (float*)d_ws;
  unsigned* wsu = (unsigned*)d_ws;

  phikey_kernel<<<64, 64, 0, stream>>>(tseq, pW1, pb1, pW2, pb2, pW3, pb3, diff_log, ws);
  stable2b_kernel<<<NRAW / 256, 256, 0, stream>>>(wsu, ws);
  sim4_kernel<<<32, 1024, 0, stream>>>(state_init, tseq, dW1, db1, dW2, db2,
                                       dW3, db3, ws, (float*)d_out);
}